// Round 10
// baseline (370.890 us; speedup 1.0000x reference)
//
#include <hip/hip_runtime.h>
#include <math.h>

#define B_   4
#define S_   4096
#define D_   1024
#define HD_  64

// ---------------- split-K flash constants ----------------
#define CK            8          // k-tiles (of 64 keys) per chunk
#define CHUNKS_PER_B  288        // sum_{qi=0}^{63} (qi/8 + 1)  (partial slots)
#define FULL_CHUNKS   224        // sum_{qi=0}^{63} (qi/8)      (8-iter chunks/batch)
#define PSTRIDE       68         // floats per row in a partial slot (o[64], m, l, pad)
#define SLOT_F        (64 * PSTRIDE)

typedef float  f32x4  __attribute__((ext_vector_type(4)));
typedef __bf16 bf16x8 __attribute__((ext_vector_type(8)));

static __device__ __forceinline__ unsigned short f2bf(float f) {
    unsigned int u = __float_as_uint(f);
    u += 0x7FFFu + ((u >> 16) & 1u);          // round-to-nearest-even
    return (unsigned short)(u >> 16);
}

// slot index of (qi, c) within a batch: qi + sum_{j<qi}(j>>3) + c
static __device__ __forceinline__ int chunk_slot(int qi, int c) {
    const int a = qi >> 3, r = qi & 7;
    return qi + 4 * a * (a - 1) + a * r + c;
}

// ------------------------------------------------------------------
// Kernel 1: QKV projection via bf16 MFMA (16x16x32), BK=128.
// R7 structure; W now staged fp32->bf16 in-loop (convert_w kernel
// deleted; W is 0.8 MB, L3-hot, so fp32 re-reads are free).
// grid = (512, 2): 32 rows x 96 cols per block, 4 blocks/CU.
// Outputs bf16: qbf (pre-scaled 0.125), kbf row-major; vt[b][h][s].
// Fragment layouts (validated R3-R9):
//   A: lane elem j = A[m = lane&15][k = (lane>>4)*8 + j]
//   B: lane elem j = B[k = (lane>>4)*8 + j][n = lane&15]
//   C/D: reg r -> row = (lane>>4)*4 + r, col = lane&15
// ------------------------------------------------------------------
__global__ __launch_bounds__(256) void proj_mfma(
    const float* __restrict__ x,
    const float* __restrict__ wq, const float* __restrict__ wk,
    const float* __restrict__ wv,
    const float* __restrict__ bq, const float* __restrict__ bk,
    const float* __restrict__ bv,
    unsigned short* __restrict__ qbf, unsigned short* __restrict__ kbf,
    unsigned short* __restrict__ vtb)
{
    __shared__ unsigned short xs[32][136];    // 8704 B
    __shared__ unsigned short wsh[96][136];   // 26112 B

    const int t = threadIdx.x;
    const int w = t >> 6, lane = t & 63;
    const int n = lane & 15, g = lane >> 4;
    const int koff = 8 * g;
    const int rt = w & 1, cg = w >> 1;
    const size_t row0 = (size_t)blockIdx.x * 32;
    const int colbase = 96 * blockIdx.y;

    f32x4 acc[3];
#pragma unroll
    for (int i = 0; i < 3; ++i) acc[i] = (f32x4)0.f;

    for (int chunk = 0; chunk < 8; ++chunk) {
        const int d0 = chunk * 128;
        __syncthreads();
        // stage x: 32 rows x 128 d, fp32 -> bf16 (4 float4/thread)
#pragma unroll
        for (int i = 0; i < 4; ++i) {
            int e = t + i * 256;              // 0..1023 float4
            int r = e >> 5, c4 = (e & 31) * 4;
            float4 v = *(const float4*)&x[(row0 + r) * D_ + d0 + c4];
            ushort4 o;
            o.x = f2bf(v.x); o.y = f2bf(v.y); o.z = f2bf(v.z); o.w = f2bf(v.w);
            *(ushort4*)&xs[r][c4] = o;
        }
        // stage w: 96 cols x 128 d, fp32 -> bf16 (12 float4/thread)
#pragma unroll
        for (int i = 0; i < 12; ++i) {
            int e = t + i * 256;              // 0..3071 float4
            int col = e >> 5;                 // 32 float4 per col
            int c4 = (e & 31) * 4;
            const int gcol = colbase + col;
            const int p = gcol >> 6, h = gcol & 63;
            const float* src = (p == 0 ? wq : (p == 1 ? wk : wv)) + (size_t)h * D_;
            float4 v = *(const float4*)&src[d0 + c4];
            ushort4 o;
            o.x = f2bf(v.x); o.y = f2bf(v.y); o.z = f2bf(v.z); o.w = f2bf(v.w);
            *(ushort4*)&wsh[col][c4] = o;
        }
        __syncthreads();

#pragma unroll
        for (int ks = 0; ks < 4; ++ks) {
            const int k0 = 32 * ks;
            const bf16x8 a = *(const bf16x8*)&xs[16 * rt + n][k0 + koff];
#pragma unroll
            for (int ci = 0; ci < 3; ++ci) {
                const bf16x8 b = *(const bf16x8*)&wsh[48 * cg + 16 * ci + n][k0 + koff];
                acc[ci] = __builtin_amdgcn_mfma_f32_16x16x32_bf16(a, b, acc[ci], 0, 0, 0);
            }
        }
    }

#pragma unroll
    for (int ci = 0; ci < 3; ++ci) {
        const int gct = 6 * blockIdx.y + 3 * cg + ci;
        const int p = gct >> 2, h0 = (gct & 3) * 16;
        const int h = h0 + n;
        const float bb = (p == 0 ? bq : (p == 1 ? bk : bv))[h];
        if (p == 2) {
            const size_t grow0 = row0 + 16 * rt + 4 * g;
            const int bidx = (int)(grow0 >> 12);
            const int s0 = (int)(grow0 & 4095);
            ushort4 u;
            u.x = f2bf(acc[ci][0] + bb); u.y = f2bf(acc[ci][1] + bb);
            u.z = f2bf(acc[ci][2] + bb); u.w = f2bf(acc[ci][3] + bb);
            *(ushort4*)&vtb[((size_t)bidx * HD_ + h) * S_ + s0] = u;
        } else {
            unsigned short* outp = (p == 0 ? qbf : kbf);
            const float scale = (p == 0) ? 0.125f : 1.0f;
#pragma unroll
            for (int r = 0; r < 4; ++r) {
                const size_t grow = row0 + 16 * rt + 4 * g + r;
                outp[grow * HD_ + h] = f2bf((acc[ci][r] + bb) * scale);
            }
        }
    }
}

// ------------------------------------------------------------------
// Kernel 2: split-K causal flash attention, bf16 MFMA (R9 structure)
// + fused split-K merge: each nc>1 chunk writes partials, releases
// via __threadfence() + device-scope atomicAdd on cnt[b*64+qi]; the
// last finisher (old == nc-1) acquires and performs the merge that
// the separate combine kernel used to do. cnt zeroed by memset
// before launch.
// ------------------------------------------------------------------
__global__ __launch_bounds__(256) void flash_splitk(
    const unsigned short* __restrict__ qg, const unsigned short* __restrict__ kg,
    const unsigned short* __restrict__ vt, float* __restrict__ out,
    float* part, int* cnt)
{
    __shared__ unsigned short qsh[64][72];      // 9216 B  Q rows (pre-scaled)
    __shared__ unsigned short ksh[64][72];      // 9216 B  K rows
    __shared__ unsigned short vsh[64][72];      // 9216 B  vT[h][key]
    __shared__ unsigned short psh[4][16][72];   // 9216 B  per-wave P[q][key]
    __shared__ int isLast;

    const int t    = threadIdx.x;
    const int w    = t >> 6;
    const int lane = t & 63;
    const int n    = lane & 15;      // MFMA col index
    const int g    = lane >> 4;      // MFMA row group
    const int koff = 8 * g;

    // decode blockIdx.x -> (b, qi, c), full chunks first (tail fill)
    int b, qi, c;
    {
        const int idx = blockIdx.x;
        if (idx < B_ * FULL_CHUNKS) {          // full 8-iteration chunks
            b = idx / FULL_CHUNKS;
            int rem = idx - b * FULL_CHUNKS;
            qi = 8;
            while (rem >= (qi >> 3)) { rem -= (qi >> 3); ++qi; }
            c = rem;
        } else {                               // last (partial) chunk of each qi
            const int r2 = idx - B_ * FULL_CHUNKS;
            b = r2 >> 6;
            qi = r2 & 63;
            c = qi >> 3;
        }
    }
    const int kt0 = c * CK;
    const int kt1 = min(qi, kt0 + CK - 1);
    const int nc  = (qi >> 3) + 1;

    const size_t qtile = ((size_t)b * S_ + (size_t)qi * 64) * HD_;

    // stage Q (once): 2 uint4/thread
    {
        const uint4* src = (const uint4*)(qg + qtile);
#pragma unroll
        for (int i = 0; i < 2; ++i) {
            int e = t + i * 256;                // 0..511
            int r = e >> 3, gg = e & 7;
            *(uint4*)&qsh[r][8 * gg] = src[e];
        }
    }

    f32x4 o4[4];                                 // O^T[h=16ht+4g+r][q=n]
#pragma unroll
    for (int i = 0; i < 4; ++i) o4[i] = (f32x4)0.f;
    float m_r = -INFINITY, l_r = 0.f;            // state of q = 16w+n

    for (int kt = kt0; kt <= kt1; ++kt) {
        const size_t kvbase = ((size_t)b * S_ + (size_t)kt * 64) * HD_;
        __syncthreads();                        // prev reads done (covers qsh on iter 0)
        {
            const uint4* ksrc = (const uint4*)(kg + kvbase);
#pragma unroll
            for (int i = 0; i < 2; ++i) {
                int e = t + i * 256;
                int r = e >> 3, gg = e & 7;
                *(uint4*)&ksh[r][8 * gg] = ksrc[e];
            }
#pragma unroll
            for (int i = 0; i < 2; ++i) {
                int e = t + i * 256;
                int h = e >> 3, gg = e & 7;     // vt[b][h][kt*64 + 8gg..]
                *(uint4*)&vsh[h][8 * gg] =
                    *(const uint4*)&vt[((size_t)b * HD_ + h) * S_ + kt * 64 + 8 * gg];
            }
        }
        __syncthreads();

        // ---- S^T = K . Q^T : 4 m-tiles (keys) x 16 q (col = q = n) ----
        f32x4 sc[4];
#pragma unroll
        for (int mt = 0; mt < 4; ++mt) sc[mt] = (f32x4)0.f;
#pragma unroll
        for (int ks = 0; ks < 2; ++ks) {
            const bf16x8 bq8 = *(const bf16x8*)&qsh[16 * w + n][32 * ks + koff];
#pragma unroll
            for (int mt = 0; mt < 4; ++mt) {
                const bf16x8 ak = *(const bf16x8*)&ksh[16 * mt + n][32 * ks + koff];
                sc[mt] = __builtin_amdgcn_mfma_f32_16x16x32_bf16(ak, bq8, sc[mt], 0, 0, 0);
            }
        }

        // ---- causal mask (diagonal k-tile only) ----
        if (kt == qi) {
            const int qloc = 16 * w + n;
#pragma unroll
            for (int mt = 0; mt < 4; ++mt)
#pragma unroll
                for (int r = 0; r < 4; ++r) {
                    const int kloc = 16 * mt + 4 * g + r;
                    if (kloc > qloc) sc[mt][r] = -INFINITY;
                }
        }

        // ---- online softmax per column q (reduce across g via shfl) ----
        float mx = -INFINITY;
#pragma unroll
        for (int mt = 0; mt < 4; ++mt)
#pragma unroll
            for (int r = 0; r < 4; ++r) mx = fmaxf(mx, sc[mt][r]);
        mx = fmaxf(mx, __shfl_xor(mx, 16));
        mx = fmaxf(mx, __shfl_xor(mx, 32));

        const float m_new = fmaxf(m_r, mx);
        const float alpha = __expf(m_r - m_new);
        float psum = 0.f;
#pragma unroll
        for (int mt = 0; mt < 4; ++mt)
#pragma unroll
            for (int r = 0; r < 4; ++r) {
                const float pe = __expf(sc[mt][r] - m_new);
                sc[mt][r] = pe;
                psum += pe;
            }
        psum += __shfl_xor(psum, 16);
        psum += __shfl_xor(psum, 32);
        l_r = l_r * alpha + psum;
        m_r = m_new;

        // rescale O (all regs have col q = n -> alpha is in-lane)
#pragma unroll
        for (int ht = 0; ht < 4; ++ht)
#pragma unroll
            for (int r = 0; r < 4; ++r) o4[ht][r] *= alpha;

        // ---- pack P^T -> per-wave LDS p[q][key] ----
#pragma unroll
        for (int mt = 0; mt < 4; ++mt) {
            ushort4 u;
            u.x = f2bf(sc[mt][0]); u.y = f2bf(sc[mt][1]);
            u.z = f2bf(sc[mt][2]); u.w = f2bf(sc[mt][3]);
            *(ushort4*)&psh[w][n][16 * mt + 4 * g] = u;
        }
        // same-wave RAW on LDS: compiler inserts lgkmcnt wait; no barrier needed

        // ---- O^T += vT . P^T  (A = vT rows, B = P^T; same LDS reads) ----
#pragma unroll
        for (int ks = 0; ks < 2; ++ks) {
            const bf16x8 ap = *(const bf16x8*)&psh[w][n][32 * ks + koff];
#pragma unroll
            for (int ht = 0; ht < 4; ++ht) {
                const bf16x8 av = *(const bf16x8*)&vsh[16 * ht + n][32 * ks + koff];
                o4[ht] = __builtin_amdgcn_mfma_f32_16x16x32_bf16(av, ap, o4[ht], 0, 0, 0);
            }
        }
    }

    const size_t qbase = ((size_t)b * S_ + (size_t)qi * 64) * HD_;
    if (nc == 1) {
        const float inv = 1.f / l_r;             // in-lane (q = 16w+n)
        const size_t ob = qbase + (size_t)(16 * w + n) * HD_;
#pragma unroll
        for (int ht = 0; ht < 4; ++ht) {
            float4 rv;
            rv.x = o4[ht][0] * inv; rv.y = o4[ht][1] * inv;
            rv.z = o4[ht][2] * inv; rv.w = o4[ht][3] * inv;
            *(float4*)&out[ob + 16 * ht + 4 * g] = rv;
        }
        return;
    }

    // ---- write this chunk's partial ----
    const size_t base0 = ((size_t)b * CHUNKS_PER_B + chunk_slot(qi, 0)) * SLOT_F;
    {
        const size_t pb = base0 + (size_t)c * SLOT_F + (size_t)(16 * w + n) * PSTRIDE;
#pragma unroll
        for (int ht = 0; ht < 4; ++ht) {
            float4 rv;
            rv.x = o4[ht][0]; rv.y = o4[ht][1];
            rv.z = o4[ht][2]; rv.w = o4[ht][3];
            *(float4*)&part[pb + 16 * ht + 4 * g] = rv;
        }
        if (g == 0) {
            part[pb + 64] = m_r;
            part[pb + 65] = l_r;
        }
    }

    // ---- release, then elect the last finisher ----
    __threadfence();                             // device-scope: partials visible
    if (t == 0) {
        const int old = atomicAdd(&cnt[b * 64 + qi], 1);   // device-scope
        isLast = (old == nc - 1);
    }
    __syncthreads();
    if (!isLast) return;
    __threadfence();                             // acquire: see other chunks' partials

    // ---- merge (identical math to the old combine kernel) ----
    {
        const int qr = t >> 2, tc = t & 3;
        float M = -INFINITY;
        for (int c0 = 0; c0 < nc; ++c0)
            M = fmaxf(M, part[base0 + (size_t)c0 * SLOT_F + qr * PSTRIDE + 64]);

        float L = 0.f;
        float o[16];
#pragma unroll
        for (int j = 0; j < 16; ++j) o[j] = 0.f;

        for (int c0 = 0; c0 < nc; ++c0) {
            const size_t sb = base0 + (size_t)c0 * SLOT_F + qr * PSTRIDE;
            const float m_c = part[sb + 64];
            const float l_c = part[sb + 65];
            const float wgt = __expf(m_c - M);
            L += wgt * l_c;
#pragma unroll
            for (int j = 0; j < 4; ++j) {
                const float4 ov = *(const float4*)&part[sb + tc * 16 + 4 * j];
                o[4 * j + 0] += wgt * ov.x; o[4 * j + 1] += wgt * ov.y;
                o[4 * j + 2] += wgt * ov.z; o[4 * j + 3] += wgt * ov.w;
            }
        }

        const float inv = 1.f / L;
#pragma unroll
        for (int j = 0; j < 4; ++j) {
            float4 r;
            r.x = o[4 * j + 0] * inv; r.y = o[4 * j + 1] * inv;
            r.z = o[4 * j + 2] * inv; r.w = o[4 * j + 3] * inv;
            *(float4*)&out[qbase + 16 * t + 4 * j] = r;
        }
    }
}

// ------------------------------------------------------------------
extern "C" void kernel_launch(void* const* d_in, const int* in_sizes, int n_in,
                              void* d_out, int out_size, void* d_ws, size_t ws_size,
                              hipStream_t stream)
{
    const float* x  = (const float*)d_in[0];
    const float* wq = (const float*)d_in[1];
    const float* bq = (const float*)d_in[2];
    const float* wk = (const float*)d_in[3];
    const float* bk = (const float*)d_in[4];
    const float* wv = (const float*)d_in[5];
    const float* bv = (const float*)d_in[6];
    float* outp = (float*)d_out;

    // ws layout: qbf | kbf | vt (bf16, n each) | part (fp32) | cnt (int)
    const size_t n = (size_t)B_ * S_ * HD_;        // 1048576
    unsigned short* qbf = (unsigned short*)d_ws;
    unsigned short* kbf = qbf + n;
    unsigned short* vtb = kbf + n;
    float* part = (float*)(vtb + n);
    int* cnt = (int*)(part + (size_t)B_ * CHUNKS_PER_B * SLOT_F);

    hipMemsetAsync(cnt, 0, (size_t)B_ * 64 * sizeof(int), stream);
    proj_mfma<<<dim3(B_ * S_ / 32, 2), 256, 0, stream>>>(
        x, wq, wk, wv, bq, bk, bv, qbf, kbf, vtb);
    flash_splitk<<<dim3(B_ * CHUNKS_PER_B), 256, 0, stream>>>(
        qbf, kbf, vtb, outp, part, cnt);
}

// Round 11
// 175.787 us; speedup vs baseline: 2.1099x; 2.1099x over previous
//
#include <hip/hip_runtime.h>
#include <math.h>

#define B_   4
#define S_   4096
#define D_   1024
#define HD_  64

// ---------------- split-K flash constants ----------------
#define CK            8          // k-tiles (of 64 keys) per chunk
#define CHUNKS_PER_B  288        // sum_{qi=0}^{63} (qi/8 + 1)  (partial slots)
#define FULL_CHUNKS   224        // sum_{qi=0}^{63} (qi/8)      (8-iter chunks/batch)
#define PSTRIDE       68         // floats per row in a partial slot (o[64], m, l, pad)
#define SLOT_F        (64 * PSTRIDE)

typedef float  f32x4  __attribute__((ext_vector_type(4)));
typedef __bf16 bf16x8 __attribute__((ext_vector_type(8)));

static __device__ __forceinline__ unsigned short f2bf(float f) {
    unsigned int u = __float_as_uint(f);
    u += 0x7FFFu + ((u >> 16) & 1u);          // round-to-nearest-even
    return (unsigned short)(u >> 16);
}

// slot index of (qi, c) within a batch: qi + sum_{j<qi}(j>>3) + c
static __device__ __forceinline__ int chunk_slot(int qi, int c) {
    const int a = qi >> 3, r = qi & 7;
    return qi + 4 * a * (a - 1) + a * r + c;
}

// ------------------------------------------------------------------
// Kernel 1: QKV projection via bf16 MFMA (16x16x32), BK=128.
// W staged fp32->bf16 in-loop (convert_w launch deleted; W is 0.8 MB,
// L3-hot, staging loop has VALU slack). grid = (512, 2), 4 blocks/CU.
// NOTE (R6/R10 lessons): no register prefetch (spills), no in-kernel
// device fences (buffer_wbl2 stalls) — plain 2-barrier K-loop.
// Fragment layouts (validated R3-R10):
//   A: lane elem j = A[m = lane&15][k = (lane>>4)*8 + j]
//   B: lane elem j = B[k = (lane>>4)*8 + j][n = lane&15]
//   C/D: reg r -> row = (lane>>4)*4 + r, col = lane&15
// ------------------------------------------------------------------
__global__ __launch_bounds__(256) void proj_mfma(
    const float* __restrict__ x,
    const float* __restrict__ wq, const float* __restrict__ wk,
    const float* __restrict__ wv,
    const float* __restrict__ bq, const float* __restrict__ bk,
    const float* __restrict__ bv,
    unsigned short* __restrict__ qbf, unsigned short* __restrict__ kbf,
    unsigned short* __restrict__ vtb)
{
    __shared__ unsigned short xs[32][136];    // 8704 B
    __shared__ unsigned short wsh[96][136];   // 26112 B

    const int t = threadIdx.x;
    const int w = t >> 6, lane = t & 63;
    const int n = lane & 15, g = lane >> 4;
    const int koff = 8 * g;
    const int rt = w & 1, cg = w >> 1;
    const size_t row0 = (size_t)blockIdx.x * 32;
    const int colbase = 96 * blockIdx.y;

    f32x4 acc[3];
#pragma unroll
    for (int i = 0; i < 3; ++i) acc[i] = (f32x4)0.f;

    for (int chunk = 0; chunk < 8; ++chunk) {
        const int d0 = chunk * 128;
        __syncthreads();
        // stage x: 32 rows x 128 d, fp32 -> bf16 (4 float4/thread)
#pragma unroll
        for (int i = 0; i < 4; ++i) {
            int e = t + i * 256;              // 0..1023 float4
            int r = e >> 5, c4 = (e & 31) * 4;
            float4 v = *(const float4*)&x[(row0 + r) * D_ + d0 + c4];
            ushort4 o;
            o.x = f2bf(v.x); o.y = f2bf(v.y); o.z = f2bf(v.z); o.w = f2bf(v.w);
            *(ushort4*)&xs[r][c4] = o;
        }
        // stage w: 96 cols x 128 d, fp32 -> bf16 (12 float4/thread)
#pragma unroll
        for (int i = 0; i < 12; ++i) {
            int e = t + i * 256;              // 0..3071 float4
            int col = e >> 5;                 // 32 float4 per col
            int c4 = (e & 31) * 4;
            const int gcol = colbase + col;
            const int p = gcol >> 6, h = gcol & 63;
            const float* src = (p == 0 ? wq : (p == 1 ? wk : wv)) + (size_t)h * D_;
            float4 v = *(const float4*)&src[d0 + c4];
            ushort4 o;
            o.x = f2bf(v.x); o.y = f2bf(v.y); o.z = f2bf(v.z); o.w = f2bf(v.w);
            *(ushort4*)&wsh[col][c4] = o;
        }
        __syncthreads();

#pragma unroll
        for (int ks = 0; ks < 4; ++ks) {
            const int k0 = 32 * ks;
            const bf16x8 a = *(const bf16x8*)&xs[16 * rt + n][k0 + koff];
#pragma unroll
            for (int ci = 0; ci < 3; ++ci) {
                const bf16x8 b = *(const bf16x8*)&wsh[48 * cg + 16 * ci + n][k0 + koff];
                acc[ci] = __builtin_amdgcn_mfma_f32_16x16x32_bf16(a, b, acc[ci], 0, 0, 0);
            }
        }
    }

#pragma unroll
    for (int ci = 0; ci < 3; ++ci) {
        const int gct = 6 * blockIdx.y + 3 * cg + ci;
        const int p = gct >> 2, h0 = (gct & 3) * 16;
        const int h = h0 + n;
        const float bb = (p == 0 ? bq : (p == 1 ? bk : bv))[h];
        if (p == 2) {
            const size_t grow0 = row0 + 16 * rt + 4 * g;
            const int bidx = (int)(grow0 >> 12);
            const int s0 = (int)(grow0 & 4095);
            ushort4 u;
            u.x = f2bf(acc[ci][0] + bb); u.y = f2bf(acc[ci][1] + bb);
            u.z = f2bf(acc[ci][2] + bb); u.w = f2bf(acc[ci][3] + bb);
            *(ushort4*)&vtb[((size_t)bidx * HD_ + h) * S_ + s0] = u;
        } else {
            unsigned short* outp = (p == 0 ? qbf : kbf);
            const float scale = (p == 0) ? 0.125f : 1.0f;
#pragma unroll
            for (int r = 0; r < 4; ++r) {
                const size_t grow = row0 + 16 * rt + 4 * g + r;
                outp[grow * HD_ + h] = f2bf((acc[ci][r] + bb) * scale);
            }
        }
    }
}

// ------------------------------------------------------------------
// Kernel 2: split-K causal flash attention, bf16 MFMA — R9 byte-exact
// (best measured). No fences/atomics (R10 lesson).
// ------------------------------------------------------------------
__global__ __launch_bounds__(256) void flash_splitk(
    const unsigned short* __restrict__ qg, const unsigned short* __restrict__ kg,
    const unsigned short* __restrict__ vt, float* __restrict__ out,
    float* __restrict__ part)
{
    __shared__ unsigned short qsh[64][72];      // 9216 B  Q rows (pre-scaled)
    __shared__ unsigned short ksh[64][72];      // 9216 B  K rows
    __shared__ unsigned short vsh[64][72];      // 9216 B  vT[h][key]
    __shared__ unsigned short psh[4][16][72];   // 9216 B  per-wave P[q][key]

    const int t    = threadIdx.x;
    const int w    = t >> 6;
    const int lane = t & 63;
    const int n    = lane & 15;      // MFMA col index
    const int g    = lane >> 4;      // MFMA row group
    const int koff = 8 * g;

    // decode blockIdx.x -> (b, qi, c), full chunks first (tail fill)
    int b, qi, c;
    {
        const int idx = blockIdx.x;
        if (idx < B_ * FULL_CHUNKS) {          // full 8-iteration chunks
            b = idx / FULL_CHUNKS;
            int rem = idx - b * FULL_CHUNKS;
            qi = 8;
            while (rem >= (qi >> 3)) { rem -= (qi >> 3); ++qi; }
            c = rem;
        } else {                               // last (partial) chunk of each qi
            const int r2 = idx - B_ * FULL_CHUNKS;
            b = r2 >> 6;
            qi = r2 & 63;
            c = qi >> 3;
        }
    }
    const int kt0 = c * CK;
    const int kt1 = min(qi, kt0 + CK - 1);
    const int nc  = (qi >> 3) + 1;

    const size_t qtile = ((size_t)b * S_ + (size_t)qi * 64) * HD_;

    // stage Q (once): 2 uint4/thread
    {
        const uint4* src = (const uint4*)(qg + qtile);
#pragma unroll
        for (int i = 0; i < 2; ++i) {
            int e = t + i * 256;                // 0..511
            int r = e >> 3, gg = e & 7;
            *(uint4*)&qsh[r][8 * gg] = src[e];
        }
    }

    f32x4 o4[4];                                 // O^T[h=16ht+4g+r][q=n]
#pragma unroll
    for (int i = 0; i < 4; ++i) o4[i] = (f32x4)0.f;
    float m_r = -INFINITY, l_r = 0.f;            // state of q = 16w+n

    for (int kt = kt0; kt <= kt1; ++kt) {
        const size_t kvbase = ((size_t)b * S_ + (size_t)kt * 64) * HD_;
        __syncthreads();                        // prev reads done (covers qsh on iter 0)
        {
            const uint4* ksrc = (const uint4*)(kg + kvbase);
#pragma unroll
            for (int i = 0; i < 2; ++i) {
                int e = t + i * 256;
                int r = e >> 3, gg = e & 7;
                *(uint4*)&ksh[r][8 * gg] = ksrc[e];
            }
#pragma unroll
            for (int i = 0; i < 2; ++i) {
                int e = t + i * 256;
                int h = e >> 3, gg = e & 7;     // vt[b][h][kt*64 + 8gg..]
                *(uint4*)&vsh[h][8 * gg] =
                    *(const uint4*)&vt[((size_t)b * HD_ + h) * S_ + kt * 64 + 8 * gg];
            }
        }
        __syncthreads();

        // ---- S^T = K . Q^T : 4 m-tiles (keys) x 16 q (col = q = n) ----
        f32x4 sc[4];
#pragma unroll
        for (int mt = 0; mt < 4; ++mt) sc[mt] = (f32x4)0.f;
#pragma unroll
        for (int ks = 0; ks < 2; ++ks) {
            const bf16x8 bq8 = *(const bf16x8*)&qsh[16 * w + n][32 * ks + koff];
#pragma unroll
            for (int mt = 0; mt < 4; ++mt) {
                const bf16x8 ak = *(const bf16x8*)&ksh[16 * mt + n][32 * ks + koff];
                sc[mt] = __builtin_amdgcn_mfma_f32_16x16x32_bf16(ak, bq8, sc[mt], 0, 0, 0);
            }
        }

        // ---- causal mask (diagonal k-tile only) ----
        if (kt == qi) {
            const int qloc = 16 * w + n;
#pragma unroll
            for (int mt = 0; mt < 4; ++mt)
#pragma unroll
                for (int r = 0; r < 4; ++r) {
                    const int kloc = 16 * mt + 4 * g + r;
                    if (kloc > qloc) sc[mt][r] = -INFINITY;
                }
        }

        // ---- online softmax per column q (reduce across g via shfl) ----
        float mx = -INFINITY;
#pragma unroll
        for (int mt = 0; mt < 4; ++mt)
#pragma unroll
            for (int r = 0; r < 4; ++r) mx = fmaxf(mx, sc[mt][r]);
        mx = fmaxf(mx, __shfl_xor(mx, 16));
        mx = fmaxf(mx, __shfl_xor(mx, 32));

        const float m_new = fmaxf(m_r, mx);
        const float alpha = __expf(m_r - m_new);
        float psum = 0.f;
#pragma unroll
        for (int mt = 0; mt < 4; ++mt)
#pragma unroll
            for (int r = 0; r < 4; ++r) {
                const float pe = __expf(sc[mt][r] - m_new);
                sc[mt][r] = pe;
                psum += pe;
            }
        psum += __shfl_xor(psum, 16);
        psum += __shfl_xor(psum, 32);
        l_r = l_r * alpha + psum;
        m_r = m_new;

        // rescale O (all regs have col q = n -> alpha is in-lane)
#pragma unroll
        for (int ht = 0; ht < 4; ++ht)
#pragma unroll
            for (int r = 0; r < 4; ++r) o4[ht][r] *= alpha;

        // ---- pack P^T -> per-wave LDS p[q][key] ----
#pragma unroll
        for (int mt = 0; mt < 4; ++mt) {
            ushort4 u;
            u.x = f2bf(sc[mt][0]); u.y = f2bf(sc[mt][1]);
            u.z = f2bf(sc[mt][2]); u.w = f2bf(sc[mt][3]);
            *(ushort4*)&psh[w][n][16 * mt + 4 * g] = u;
        }
        // same-wave RAW on LDS: compiler inserts lgkmcnt wait; no barrier needed

        // ---- O^T += vT . P^T  (A = vT rows, B = P^T; same LDS reads) ----
#pragma unroll
        for (int ks = 0; ks < 2; ++ks) {
            const bf16x8 ap = *(const bf16x8*)&psh[w][n][32 * ks + koff];
#pragma unroll
            for (int ht = 0; ht < 4; ++ht) {
                const bf16x8 av = *(const bf16x8*)&vsh[16 * ht + n][32 * ks + koff];
                o4[ht] = __builtin_amdgcn_mfma_f32_16x16x32_bf16(av, ap, o4[ht], 0, 0, 0);
            }
        }
    }

    const size_t qbase = ((size_t)b * S_ + (size_t)qi * 64) * HD_;
    if (nc == 1) {
        const float inv = 1.f / l_r;             // in-lane (q = 16w+n)
        const size_t ob = qbase + (size_t)(16 * w + n) * HD_;
#pragma unroll
        for (int ht = 0; ht < 4; ++ht) {
            float4 rv;
            rv.x = o4[ht][0] * inv; rv.y = o4[ht][1] * inv;
            rv.z = o4[ht][2] * inv; rv.w = o4[ht][3] * inv;
            *(float4*)&out[ob + 16 * ht + 4 * g] = rv;
        }
    } else {
        const size_t sb = ((size_t)b * CHUNKS_PER_B + chunk_slot(qi, c)) * SLOT_F;
        const size_t pb = sb + (size_t)(16 * w + n) * PSTRIDE;
#pragma unroll
        for (int ht = 0; ht < 4; ++ht) {
            float4 rv;
            rv.x = o4[ht][0]; rv.y = o4[ht][1];
            rv.z = o4[ht][2]; rv.w = o4[ht][3];
            *(float4*)&part[pb + 16 * ht + 4 * g] = rv;
        }
        if (g == 0) {
            part[pb + 64] = m_r;
            part[pb + 65] = l_r;
        }
    }
}

// ------------------------------------------------------------------
// Kernel 3: merge partials for qi >= CK.  grid = (56, B). R9 exact.
// ------------------------------------------------------------------
__global__ __launch_bounds__(256) void combine(
    const float* __restrict__ part, float* __restrict__ out)
{
    const int t  = threadIdx.x;
    const int qr = t >> 2, tc = t & 3;
    const int qi = blockIdx.x + CK;          // 8..63
    const int b  = blockIdx.y;
    const int nc = (qi >> 3) + 1;

    const size_t base0 = ((size_t)b * CHUNKS_PER_B + chunk_slot(qi, 0)) * SLOT_F;

    float M = -INFINITY;
    for (int c0 = 0; c0 < nc; ++c0)
        M = fmaxf(M, part[base0 + (size_t)c0 * SLOT_F + qr * PSTRIDE + 64]);

    float L = 0.f;
    float o[16];
#pragma unroll
    for (int j = 0; j < 16; ++j) o[j] = 0.f;

    for (int c0 = 0; c0 < nc; ++c0) {
        const size_t sb = base0 + (size_t)c0 * SLOT_F + qr * PSTRIDE;
        const float m_c = part[sb + 64];
        const float l_c = part[sb + 65];
        const float w = __expf(m_c - M);
        L += w * l_c;
#pragma unroll
        for (int j = 0; j < 4; ++j) {
            const float4 ov = *(const float4*)&part[sb + tc * 16 + 4 * j];
            o[4 * j + 0] += w * ov.x; o[4 * j + 1] += w * ov.y;
            o[4 * j + 2] += w * ov.z; o[4 * j + 3] += w * ov.w;
        }
    }

    const float inv = 1.f / L;
    const size_t qbase = ((size_t)b * S_ + (size_t)qi * 64) * HD_;
#pragma unroll
    for (int j = 0; j < 4; ++j) {
        float4 r;
        r.x = o[4 * j + 0] * inv; r.y = o[4 * j + 1] * inv;
        r.z = o[4 * j + 2] * inv; r.w = o[4 * j + 3] * inv;
        *(float4*)&out[qbase + 16 * t + 4 * j] = r;
    }
}

// ------------------------------------------------------------------
extern "C" void kernel_launch(void* const* d_in, const int* in_sizes, int n_in,
                              void* d_out, int out_size, void* d_ws, size_t ws_size,
                              hipStream_t stream)
{
    const float* x  = (const float*)d_in[0];
    const float* wq = (const float*)d_in[1];
    const float* bq = (const float*)d_in[2];
    const float* wk = (const float*)d_in[3];
    const float* bk = (const float*)d_in[4];
    const float* wv = (const float*)d_in[5];
    const float* bv = (const float*)d_in[6];
    float* outp = (float*)d_out;

    // ws layout: qbf | kbf | vt (bf16, n each) | part (fp32)
    const size_t n = (size_t)B_ * S_ * HD_;        // 1048576
    unsigned short* qbf = (unsigned short*)d_ws;
    unsigned short* kbf = qbf + n;
    unsigned short* vtb = kbf + n;
    float* part = (float*)(vtb + n);

    proj_mfma<<<dim3(B_ * S_ / 32, 2), 256, 0, stream>>>(
        x, wq, wk, wv, bq, bk, bv, qbf, kbf, vtb);
    flash_splitk<<<dim3(B_ * CHUNKS_PER_B), 256, 0, stream>>>(
        qbf, kbf, vtb, outp, part);
    combine<<<dim3(S_ / 64 - CK, B_), 256, 0, stream>>>(part, outp);
}

// Round 12
// 154.803 us; speedup vs baseline: 2.3959x; 1.1356x over previous
//
#include <hip/hip_runtime.h>
#include <math.h>

#define B_   4
#define S_   4096
#define D_   1024
#define HD_  64

// ---------------- split-K flash constants ----------------
#define CK            8          // k-tiles (of 64 keys) per chunk
#define CHUNKS_PER_B  288        // sum_{qi=0}^{63} (qi/8 + 1)  (partial slots)
#define FULL_CHUNKS   224        // sum_{qi=0}^{63} (qi/8)      (8-iter chunks/batch)
#define PSTRIDE       68         // floats per row in a partial slot (o[64], m, l, pad)
#define SLOT_F        (64 * PSTRIDE)

typedef float  f32x4  __attribute__((ext_vector_type(4)));
typedef __bf16 bf16x8 __attribute__((ext_vector_type(8)));

static __device__ __forceinline__ unsigned short f2bf(float f) {
    unsigned int u = __float_as_uint(f);
    u += 0x7FFFu + ((u >> 16) & 1u);          // round-to-nearest-even
    return (unsigned short)(u >> 16);
}

// slot index of (qi, c) within a batch: qi + sum_{j<qi}(j>>3) + c
static __device__ __forceinline__ int chunk_slot(int qi, int c) {
    const int a = qi >> 3, r = qi & 7;
    return qi + 4 * a * (a - 1) + a * r + c;
}

// ------------------------------------------------------------------
// Kernel 0: convert wq/wk/wv (fp32 [64][1024]) into wbf (bf16 [192][1024]).
// KEEP SEPARATE (R11 lesson): folding this into proj staging doubles
// proj's per-barrier staging bytes and adds f2bf to the critical path.
// ------------------------------------------------------------------
__global__ __launch_bounds__(256) void convert_w(
    const float* __restrict__ wq, const float* __restrict__ wk,
    const float* __restrict__ wv, unsigned short* __restrict__ wbf)
{
    const int col = blockIdx.x;            // 0..191
    const int p = col >> 6, h = col & 63;
    const float* src = (p == 0 ? wq : (p == 1 ? wk : wv)) + (size_t)h * D_;
    const int t = threadIdx.x;
    const float4 v = ((const float4*)src)[t];
    ushort4 o;
    o.x = f2bf(v.x); o.y = f2bf(v.y); o.z = f2bf(v.z); o.w = f2bf(v.w);
    *(ushort4*)&wbf[(size_t)col * D_ + 4 * t] = o;
}

// ------------------------------------------------------------------
// Kernel 1: QKV projection via bf16 MFMA (16x16x32), BK=128.
// R7/R9 exact (measured best). grid = (512, 2), 4 blocks/CU.
// NOTE (R6/R10/R11 lessons): no register prefetch (spills), no fences,
// W staged from pre-converted bf16 (half the staging bytes).
// Fragment layouts (validated R3-R11):
//   A: lane elem j = A[m = lane&15][k = (lane>>4)*8 + j]
//   B: lane elem j = B[k = (lane>>4)*8 + j][n = lane&15]
//   C/D: reg r -> row = (lane>>4)*4 + r, col = lane&15
// ------------------------------------------------------------------
__global__ __launch_bounds__(256) void proj_mfma(
    const float* __restrict__ x, const unsigned short* __restrict__ wbf,
    const float* __restrict__ bq, const float* __restrict__ bk,
    const float* __restrict__ bv,
    unsigned short* __restrict__ qbf, unsigned short* __restrict__ kbf,
    unsigned short* __restrict__ vtb)
{
    __shared__ unsigned short xs[32][136];    // 8704 B
    __shared__ unsigned short wsh[96][136];   // 26112 B

    const int t = threadIdx.x;
    const int w = t >> 6, lane = t & 63;
    const int n = lane & 15, g = lane >> 4;
    const int koff = 8 * g;
    const int rt = w & 1, cg = w >> 1;
    const size_t row0 = (size_t)blockIdx.x * 32;
    const int colbase = 96 * blockIdx.y;

    f32x4 acc[3];
#pragma unroll
    for (int i = 0; i < 3; ++i) acc[i] = (f32x4)0.f;

    for (int chunk = 0; chunk < 8; ++chunk) {
        const int d0 = chunk * 128;
        __syncthreads();
        // stage x: 32 rows x 128 d, fp32 -> bf16 (4 float4/thread)
#pragma unroll
        for (int i = 0; i < 4; ++i) {
            int e = t + i * 256;              // 0..1023 float4
            int r = e >> 5, c4 = (e & 31) * 4;
            float4 v = *(const float4*)&x[(row0 + r) * D_ + d0 + c4];
            ushort4 o;
            o.x = f2bf(v.x); o.y = f2bf(v.y); o.z = f2bf(v.z); o.w = f2bf(v.w);
            *(ushort4*)&xs[r][c4] = o;
        }
        // stage w: 96 cols x 128 d bf16 (6 uint4/thread)
#pragma unroll
        for (int i = 0; i < 6; ++i) {
            int e = t + i * 256;              // 0..1535
            int col = e >> 4, g8 = (e & 15) * 8;
            uint4 v = *(const uint4*)&wbf[(size_t)(colbase + col) * D_ + d0 + g8];
            *(uint4*)&wsh[col][g8] = v;
        }
        __syncthreads();

#pragma unroll
        for (int ks = 0; ks < 4; ++ks) {
            const int k0 = 32 * ks;
            const bf16x8 a = *(const bf16x8*)&xs[16 * rt + n][k0 + koff];
#pragma unroll
            for (int ci = 0; ci < 3; ++ci) {
                const bf16x8 b = *(const bf16x8*)&wsh[48 * cg + 16 * ci + n][k0 + koff];
                acc[ci] = __builtin_amdgcn_mfma_f32_16x16x32_bf16(a, b, acc[ci], 0, 0, 0);
            }
        }
    }

#pragma unroll
    for (int ci = 0; ci < 3; ++ci) {
        const int gct = 6 * blockIdx.y + 3 * cg + ci;
        const int p = gct >> 2, h0 = (gct & 3) * 16;
        const int h = h0 + n;
        const float bb = (p == 0 ? bq : (p == 1 ? bk : bv))[h];
        if (p == 2) {
            const size_t grow0 = row0 + 16 * rt + 4 * g;
            const int bidx = (int)(grow0 >> 12);
            const int s0 = (int)(grow0 & 4095);
            ushort4 u;
            u.x = f2bf(acc[ci][0] + bb); u.y = f2bf(acc[ci][1] + bb);
            u.z = f2bf(acc[ci][2] + bb); u.w = f2bf(acc[ci][3] + bb);
            *(ushort4*)&vtb[((size_t)bidx * HD_ + h) * S_ + s0] = u;
        } else {
            unsigned short* outp = (p == 0 ? qbf : kbf);
            const float scale = (p == 0) ? 0.125f : 1.0f;
#pragma unroll
            for (int r = 0; r < 4; ++r) {
                const size_t grow = row0 + 16 * rt + 4 * g + r;
                outp[grow * HD_ + h] = f2bf((acc[ci][r] + bb) * scale);
            }
        }
    }
}

// ------------------------------------------------------------------
// Kernel 2: split-K causal flash attention, bf16 MFMA — R9 byte-exact
// (best measured). No fences/atomics (R10 lesson).
// ------------------------------------------------------------------
__global__ __launch_bounds__(256) void flash_splitk(
    const unsigned short* __restrict__ qg, const unsigned short* __restrict__ kg,
    const unsigned short* __restrict__ vt, float* __restrict__ out,
    float* __restrict__ part)
{
    __shared__ unsigned short qsh[64][72];      // 9216 B  Q rows (pre-scaled)
    __shared__ unsigned short ksh[64][72];      // 9216 B  K rows
    __shared__ unsigned short vsh[64][72];      // 9216 B  vT[h][key]
    __shared__ unsigned short psh[4][16][72];   // 9216 B  per-wave P[q][key]

    const int t    = threadIdx.x;
    const int w    = t >> 6;
    const int lane = t & 63;
    const int n    = lane & 15;      // MFMA col index
    const int g    = lane >> 4;      // MFMA row group
    const int koff = 8 * g;

    // decode blockIdx.x -> (b, qi, c), full chunks first (tail fill)
    int b, qi, c;
    {
        const int idx = blockIdx.x;
        if (idx < B_ * FULL_CHUNKS) {          // full 8-iteration chunks
            b = idx / FULL_CHUNKS;
            int rem = idx - b * FULL_CHUNKS;
            qi = 8;
            while (rem >= (qi >> 3)) { rem -= (qi >> 3); ++qi; }
            c = rem;
        } else {                               // last (partial) chunk of each qi
            const int r2 = idx - B_ * FULL_CHUNKS;
            b = r2 >> 6;
            qi = r2 & 63;
            c = qi >> 3;
        }
    }
    const int kt0 = c * CK;
    const int kt1 = min(qi, kt0 + CK - 1);
    const int nc  = (qi >> 3) + 1;

    const size_t qtile = ((size_t)b * S_ + (size_t)qi * 64) * HD_;

    // stage Q (once): 2 uint4/thread
    {
        const uint4* src = (const uint4*)(qg + qtile);
#pragma unroll
        for (int i = 0; i < 2; ++i) {
            int e = t + i * 256;                // 0..511
            int r = e >> 3, gg = e & 7;
            *(uint4*)&qsh[r][8 * gg] = src[e];
        }
    }

    f32x4 o4[4];                                 // O^T[h=16ht+4g+r][q=n]
#pragma unroll
    for (int i = 0; i < 4; ++i) o4[i] = (f32x4)0.f;
    float m_r = -INFINITY, l_r = 0.f;            // state of q = 16w+n

    for (int kt = kt0; kt <= kt1; ++kt) {
        const size_t kvbase = ((size_t)b * S_ + (size_t)kt * 64) * HD_;
        __syncthreads();                        // prev reads done (covers qsh on iter 0)
        {
            const uint4* ksrc = (const uint4*)(kg + kvbase);
#pragma unroll
            for (int i = 0; i < 2; ++i) {
                int e = t + i * 256;
                int r = e >> 3, gg = e & 7;
                *(uint4*)&ksh[r][8 * gg] = ksrc[e];
            }
#pragma unroll
            for (int i = 0; i < 2; ++i) {
                int e = t + i * 256;
                int h = e >> 3, gg = e & 7;     // vt[b][h][kt*64 + 8gg..]
                *(uint4*)&vsh[h][8 * gg] =
                    *(const uint4*)&vt[((size_t)b * HD_ + h) * S_ + kt * 64 + 8 * gg];
            }
        }
        __syncthreads();

        // ---- S^T = K . Q^T : 4 m-tiles (keys) x 16 q (col = q = n) ----
        f32x4 sc[4];
#pragma unroll
        for (int mt = 0; mt < 4; ++mt) sc[mt] = (f32x4)0.f;
#pragma unroll
        for (int ks = 0; ks < 2; ++ks) {
            const bf16x8 bq8 = *(const bf16x8*)&qsh[16 * w + n][32 * ks + koff];
#pragma unroll
            for (int mt = 0; mt < 4; ++mt) {
                const bf16x8 ak = *(const bf16x8*)&ksh[16 * mt + n][32 * ks + koff];
                sc[mt] = __builtin_amdgcn_mfma_f32_16x16x32_bf16(ak, bq8, sc[mt], 0, 0, 0);
            }
        }

        // ---- causal mask (diagonal k-tile only) ----
        if (kt == qi) {
            const int qloc = 16 * w + n;
#pragma unroll
            for (int mt = 0; mt < 4; ++mt)
#pragma unroll
                for (int r = 0; r < 4; ++r) {
                    const int kloc = 16 * mt + 4 * g + r;
                    if (kloc > qloc) sc[mt][r] = -INFINITY;
                }
        }

        // ---- online softmax per column q (reduce across g via shfl) ----
        float mx = -INFINITY;
#pragma unroll
        for (int mt = 0; mt < 4; ++mt)
#pragma unroll
            for (int r = 0; r < 4; ++r) mx = fmaxf(mx, sc[mt][r]);
        mx = fmaxf(mx, __shfl_xor(mx, 16));
        mx = fmaxf(mx, __shfl_xor(mx, 32));

        const float m_new = fmaxf(m_r, mx);
        const float alpha = __expf(m_r - m_new);
        float psum = 0.f;
#pragma unroll
        for (int mt = 0; mt < 4; ++mt)
#pragma unroll
            for (int r = 0; r < 4; ++r) {
                const float pe = __expf(sc[mt][r] - m_new);
                sc[mt][r] = pe;
                psum += pe;
            }
        psum += __shfl_xor(psum, 16);
        psum += __shfl_xor(psum, 32);
        l_r = l_r * alpha + psum;
        m_r = m_new;

        // rescale O (all regs have col q = n -> alpha is in-lane)
#pragma unroll
        for (int ht = 0; ht < 4; ++ht)
#pragma unroll
            for (int r = 0; r < 4; ++r) o4[ht][r] *= alpha;

        // ---- pack P^T -> per-wave LDS p[q][key] ----
#pragma unroll
        for (int mt = 0; mt < 4; ++mt) {
            ushort4 u;
            u.x = f2bf(sc[mt][0]); u.y = f2bf(sc[mt][1]);
            u.z = f2bf(sc[mt][2]); u.w = f2bf(sc[mt][3]);
            *(ushort4*)&psh[w][n][16 * mt + 4 * g] = u;
        }
        // same-wave RAW on LDS: compiler inserts lgkmcnt wait; no barrier needed

        // ---- O^T += vT . P^T  (A = vT rows, B = P^T; same LDS reads) ----
#pragma unroll
        for (int ks = 0; ks < 2; ++ks) {
            const bf16x8 ap = *(const bf16x8*)&psh[w][n][32 * ks + koff];
#pragma unroll
            for (int ht = 0; ht < 4; ++ht) {
                const bf16x8 av = *(const bf16x8*)&vsh[16 * ht + n][32 * ks + koff];
                o4[ht] = __builtin_amdgcn_mfma_f32_16x16x32_bf16(av, ap, o4[ht], 0, 0, 0);
            }
        }
    }

    const size_t qbase = ((size_t)b * S_ + (size_t)qi * 64) * HD_;
    if (nc == 1) {
        const float inv = 1.f / l_r;             // in-lane (q = 16w+n)
        const size_t ob = qbase + (size_t)(16 * w + n) * HD_;
#pragma unroll
        for (int ht = 0; ht < 4; ++ht) {
            float4 rv;
            rv.x = o4[ht][0] * inv; rv.y = o4[ht][1] * inv;
            rv.z = o4[ht][2] * inv; rv.w = o4[ht][3] * inv;
            *(float4*)&out[ob + 16 * ht + 4 * g] = rv;
        }
    } else {
        const size_t sb = ((size_t)b * CHUNKS_PER_B + chunk_slot(qi, c)) * SLOT_F;
        const size_t pb = sb + (size_t)(16 * w + n) * PSTRIDE;
#pragma unroll
        for (int ht = 0; ht < 4; ++ht) {
            float4 rv;
            rv.x = o4[ht][0]; rv.y = o4[ht][1];
            rv.z = o4[ht][2]; rv.w = o4[ht][3];
            *(float4*)&part[pb + 16 * ht + 4 * g] = rv;
        }
        if (g == 0) {
            part[pb + 64] = m_r;
            part[pb + 65] = l_r;
        }
    }
}

// ------------------------------------------------------------------
// Kernel 3: merge partials for qi >= CK.  grid = (56, B). R9 exact.
// ------------------------------------------------------------------
__global__ __launch_bounds__(256) void combine(
    const float* __restrict__ part, float* __restrict__ out)
{
    const int t  = threadIdx.x;
    const int qr = t >> 2, tc = t & 3;
    const int qi = blockIdx.x + CK;          // 8..63
    const int b  = blockIdx.y;
    const int nc = (qi >> 3) + 1;

    const size_t base0 = ((size_t)b * CHUNKS_PER_B + chunk_slot(qi, 0)) * SLOT_F;

    float M = -INFINITY;
    for (int c0 = 0; c0 < nc; ++c0)
        M = fmaxf(M, part[base0 + (size_t)c0 * SLOT_F + qr * PSTRIDE + 64]);

    float L = 0.f;
    float o[16];
#pragma unroll
    for (int j = 0; j < 16; ++j) o[j] = 0.f;

    for (int c0 = 0; c0 < nc; ++c0) {
        const size_t sb = base0 + (size_t)c0 * SLOT_F + qr * PSTRIDE;
        const float m_c = part[sb + 64];
        const float l_c = part[sb + 65];
        const float w = __expf(m_c - M);
        L += w * l_c;
#pragma unroll
        for (int j = 0; j < 4; ++j) {
            const float4 ov = *(const float4*)&part[sb + tc * 16 + 4 * j];
            o[4 * j + 0] += w * ov.x; o[4 * j + 1] += w * ov.y;
            o[4 * j + 2] += w * ov.z; o[4 * j + 3] += w * ov.w;
        }
    }

    const float inv = 1.f / L;
    const size_t qbase = ((size_t)b * S_ + (size_t)qi * 64) * HD_;
#pragma unroll
    for (int j = 0; j < 4; ++j) {
        float4 r;
        r.x = o[4 * j + 0] * inv; r.y = o[4 * j + 1] * inv;
        r.z = o[4 * j + 2] * inv; r.w = o[4 * j + 3] * inv;
        *(float4*)&out[qbase + 16 * t + 4 * j] = r;
    }
}

// ------------------------------------------------------------------
extern "C" void kernel_launch(void* const* d_in, const int* in_sizes, int n_in,
                              void* d_out, int out_size, void* d_ws, size_t ws_size,
                              hipStream_t stream)
{
    const float* x  = (const float*)d_in[0];
    const float* wq = (const float*)d_in[1];
    const float* bq = (const float*)d_in[2];
    const float* wk = (const float*)d_in[3];
    const float* bk = (const float*)d_in[4];
    const float* wv = (const float*)d_in[5];
    const float* bv = (const float*)d_in[6];
    float* outp = (float*)d_out;

    // ws layout: qbf | kbf | vt (bf16, n each) | wbf (bf16) | part (fp32)
    const size_t n = (size_t)B_ * S_ * HD_;        // 1048576
    unsigned short* qbf = (unsigned short*)d_ws;
    unsigned short* kbf = qbf + n;
    unsigned short* vtb = kbf + n;
    unsigned short* wbf = vtb + n;                 // 192*1024 bf16
    float* part = (float*)(wbf + (size_t)192 * D_);

    convert_w<<<dim3(192), 256, 0, stream>>>(wq, wk, wv, wbf);
    proj_mfma<<<dim3(B_ * S_ / 32, 2), 256, 0, stream>>>(
        x, wbf, bq, bk, bv, qbf, kbf, vtb);
    flash_splitk<<<dim3(B_ * CHUNKS_PER_B), 256, 0, stream>>>(
        qbf, kbf, vtb, outp, part);
    combine<<<dim3(S_ / 64 - CK, B_), 256, 0, stream>>>(part, outp);
}